// Round 8
// baseline (208.507 us; speedup 1.0000x reference)
//
#include <hip/hip_runtime.h>
#include <hip/hip_bf16.h>
#include <cstdint>

// Problem constants
#define B_ 4
#define T_ 1024
#define W_ 33
#define F_ 512
#define H_ 8
#define DK_ 64

typedef __attribute__((ext_vector_type(8))) short short8;
typedef __attribute__((ext_vector_type(4))) float f32x4;

__device__ __forceinline__ float b2f(ushort u) {
  return __uint_as_float(((uint32_t)u) << 16);
}
__device__ __forceinline__ ushort f2b(float f) {
  union { __hip_bfloat16 b; ushort u; } cv;
  cv.b = __float2bfloat16(f);
  return cv.u;
}

// ---------------------------------------------------------------------------
// Weight convert.
// which=0,2,3 (Wq,Wv,Wo): orig MFMA-frag order for B[n,k]=W[k,n]:
//   dst[((nt*16+kc)*64+l)*8+e] = W[k,n], n=nt*16+(l&15), k=kc*32+(l>>4)*8+e
// which=1 (Wk): per-head TRANSPOSED table for R-GEMM, B[n=f,k=d]=Wk[f,h*64+d]:
//   dst[(((h*32+ntf)*2+kc)*64+l)*8+e] = Wk[ntf*16+(l&15), h*64+kc*32+(l>>4)*8+e]
// ---------------------------------------------------------------------------
__global__ void convert_w(const float* __restrict__ Wq, const float* __restrict__ Wk,
                          const float* __restrict__ Wv, const float* __restrict__ Wo,
                          ushort* __restrict__ out)
{
  int which = blockIdx.y;
  const float* src = (which == 0) ? Wq : (which == 1) ? Wk : (which == 2) ? Wv : Wo;
  ushort* dst = out + (size_t)which * 262144;
  int idx = blockIdx.x * 256 + threadIdx.x;     // 0 .. 262143
  int e = idx & 7;
  int l = (idx >> 3) & 63;
  float v;
  if (which == 1) {
    int kc  = (idx >> 9) & 1;
    int ntf = (idx >> 10) & 31;
    int h   = idx >> 15;
    v = src[(size_t)(ntf * 16 + (l & 15)) * 512 + h * 64 + kc * 32 + ((l >> 4) << 3) + e];
  } else {
    int kc = (idx >> 9) & 15;
    int nt = idx >> 13;
    int k = kc * 32 + ((l >> 4) << 3) + e;
    int n = (nt << 4) + (l & 15);
    v = src[(size_t)k * 512 + n];
  }
  dst[idx] = f2b(v);
}

// ---------------------------------------------------------------------------
// Pipelined GEMM (q-proj / O-proj): C[M x 512] = (A[M x 512] @ W + bias)*scale
// ---------------------------------------------------------------------------
template<bool A_F32, bool OUT_F32>
__global__ __launch_bounds__(256, 2)
void gemm_pipe(const void* __restrict__ Ap, const ushort* __restrict__ Bf,
               const float* __restrict__ bias, void* __restrict__ Cp, float scale)
{
  __shared__ ushort lA[3][128 * 64];

  const int tid  = threadIdx.x;
  const int lane = tid & 63;
  const int wid  = tid >> 6;
  const int wr   = wid >> 1, wc = wid & 1;
  const int lrow = lane & 15;
  const int lk8  = (lane >> 4) * 8;

  int nwg  = gridDim.x;
  int xcd  = blockIdx.x & 7;
  int slot = blockIdx.x >> 3;
  int q8   = nwg >> 3, r8 = nwg & 7;
  int base = (xcd < r8) ? xcd * (q8 + 1) : r8 * (q8 + 1) + (xcd - r8) * q8;
  int L    = base + slot;
  int bm   = L >> 2;
  int bn   = L & 3;

  int lb_[4];
  size_t asrc_[4];
#pragma unroll
  for (int p = 0; p < 4; ++p) {
    int c   = p * 256 + tid;
    int row = c >> 3;
    int kc  = (c & 7) * 8;
    lb_[p]  = (row * 128 + kc * 2) ^ ((row & 7) << 4);
    asrc_[p] = (size_t)(bm * 128 + row) * 512 + kc;
  }

  const int ntb = bn * 8 + wc * 4;

  float4 P0a0[4], P0a1[4], P1a0[4], P1a1[4];
  short8 P0r[4], P1r[4];
  short8 Q0[8], Q1[8];

  auto issueA = [&](int ks, float4 (&d0)[4], float4 (&d1)[4], short8 (&dr)[4]) {
#pragma unroll
    for (int p = 0; p < 4; ++p) {
      if (A_F32) {
        const float* src = (const float*)Ap + asrc_[p] + ks * 64;
        d0[p] = *(const float4*)src;
        d1[p] = *(const float4*)(src + 4);
      } else {
        dr[p] = *(const short8*)((const ushort*)Ap + asrc_[p] + ks * 64);
      }
    }
  };
  auto lwriteA = [&](int buf, float4 (&d0)[4], float4 (&d1)[4], short8 (&dr)[4]) {
#pragma unroll
    for (int p = 0; p < 4; ++p) {
      short8 hv;
      if (A_F32) {
        hv[0] = (short)f2b(d0[p].x); hv[1] = (short)f2b(d0[p].y);
        hv[2] = (short)f2b(d0[p].z); hv[3] = (short)f2b(d0[p].w);
        hv[4] = (short)f2b(d1[p].x); hv[5] = (short)f2b(d1[p].y);
        hv[6] = (short)f2b(d1[p].z); hv[7] = (short)f2b(d1[p].w);
      } else {
        hv = dr[p];
      }
      *(short8*)((char*)lA[buf] + lb_[p]) = hv;
    }
  };
  auto loadB = [&](int ks, short8 (&dq)[8]) {
#pragma unroll
    for (int kk = 0; kk < 2; ++kk)
#pragma unroll
      for (int nf = 0; nf < 4; ++nf)
        dq[kk * 4 + nf] = *(const short8*)(Bf +
            (((size_t)(ntb + nf) * 16 + ks * 2 + kk) * 64 + lane) * 8);
  };

  f32x4 acc[4][4];
#pragma unroll
  for (int i = 0; i < 4; ++i)
#pragma unroll
    for (int j = 0; j < 4; ++j) acc[i][j] = {0.f, 0.f, 0.f, 0.f};

  auto computeStep = [&](int buf, short8 (&dq)[8]) {
#pragma unroll
    for (int kk = 0; kk < 2; ++kk) {
      short8 af[4];
#pragma unroll
      for (int mf = 0; mf < 4; ++mf) {
        int row = wr * 64 + mf * 16 + lrow;
        int off = (row * 128 + (kk * 32 + lk8) * 2) ^ ((row & 7) << 4);
        af[mf] = *(const short8*)((const char*)lA[buf] + off);
      }
#pragma unroll
      for (int mf = 0; mf < 4; ++mf)
#pragma unroll
        for (int nf = 0; nf < 4; ++nf)
          acc[mf][nf] = __builtin_amdgcn_mfma_f32_16x16x32_bf16(af[mf], dq[kk * 4 + nf], acc[mf][nf], 0, 0, 0);
    }
  };

  issueA(0, P0a0, P0a1, P0r);
  issueA(1, P1a0, P1a1, P1r);
  loadB(0, Q0);
  lwriteA(0, P0a0, P0a1, P0r);
  __syncthreads();

#define GSTEP(T, PWa0, PWa1, PWr, PIa0, PIa1, PIr, QW, QR)                    \
  {                                                                           \
    if ((T) + 1 < 8) lwriteA(((T) + 1) % 3, PWa0, PWa1, PWr);                 \
    if ((T) + 2 < 8) issueA((T) + 2, PIa0, PIa1, PIr);                        \
    if ((T) + 1 < 8) loadB((T) + 1, QW);                                      \
    computeStep((T) % 3, QR);                                                 \
    if ((T) < 7) __syncthreads();                                             \
  }

  GSTEP(0, P1a0, P1a1, P1r, P0a0, P0a1, P0r, Q1, Q0)
  GSTEP(1, P0a0, P0a1, P0r, P1a0, P1a1, P1r, Q0, Q1)
  GSTEP(2, P1a0, P1a1, P1r, P0a0, P0a1, P0r, Q1, Q0)
  GSTEP(3, P0a0, P0a1, P0r, P1a0, P1a1, P1r, Q0, Q1)
  GSTEP(4, P1a0, P1a1, P1r, P0a0, P0a1, P0r, Q1, Q0)
  GSTEP(5, P0a0, P0a1, P0r, P1a0, P1a1, P1r, Q0, Q1)
  GSTEP(6, P1a0, P1a1, P1r, P0a0, P0a1, P0r, Q1, Q0)
  GSTEP(7, P0a0, P0a1, P0r, P1a0, P1a1, P1r, Q0, Q1)
#undef GSTEP

  float bs[4];
#pragma unroll
  for (int nf = 0; nf < 4; ++nf)
    bs[nf] = bias[bn * 128 + wc * 64 + nf * 16 + lrow];

  const int r0 = (lane >> 4) * 4;
#pragma unroll
  for (int mf = 0; mf < 4; ++mf) {
#pragma unroll
    for (int nf = 0; nf < 4; ++nf) {
      int gcol = bn * 128 + wc * 64 + nf * 16 + lrow;
#pragma unroll
      for (int r = 0; r < 4; ++r) {
        int grow = bm * 128 + wr * 64 + mf * 16 + r0 + r;
        float val = (acc[mf][nf][r] + bs[nf]) * scale;
        if (OUT_F32) ((float*)Cp)[(size_t)grow * 512 + gcol] = val;
        else         ((ushort*)Cp)[(size_t)grow * 512 + gcol] = f2b(val);
      }
    }
  }
}

// ---------------------------------------------------------------------------
// R-GEMM: R[bt,h,f] = sum_d q[bt,h*64+d] * Wk[f,h*64+d]   (q already /8)
// ---------------------------------------------------------------------------
__global__ __launch_bounds__(256, 4)
void r_gemm(const ushort* __restrict__ q, const ushort* __restrict__ WkR,
            ushort* __restrict__ R)
{
  const int tid  = threadIdx.x;
  const int lane = tid & 63;
  const int wid  = tid >> 6;
  const int lr   = lane & 15;
  const int l8   = (lane >> 4) * 8;
  const int mg   = blockIdx.x >> 1;
  const int nh   = blockIdx.x & 1;
  const int h    = blockIdx.y;
  const int m0   = mg * 64;
  const int ntb  = nh * 16 + wid * 4;

  short8 af[2][4], bg[2][4];
#pragma unroll
  for (int ks = 0; ks < 2; ++ks)
#pragma unroll
    for (int mf = 0; mf < 4; ++mf)
      af[ks][mf] = *(const short8*)(q + (size_t)(m0 + mf * 16 + lr) * 512 + h * 64 + ks * 32 + l8);
#pragma unroll
  for (int ks = 0; ks < 2; ++ks)
#pragma unroll
    for (int nf = 0; nf < 4; ++nf)
      bg[ks][nf] = *(const short8*)(WkR + ((size_t)((h * 32 + ntb + nf) * 2 + ks) * 64 + lane) * 8);

  f32x4 acc[4][4];
#pragma unroll
  for (int i = 0; i < 4; ++i)
#pragma unroll
    for (int j = 0; j < 4; ++j) acc[i][j] = {0.f, 0.f, 0.f, 0.f};

#pragma unroll
  for (int ks = 0; ks < 2; ++ks)
#pragma unroll
    for (int mf = 0; mf < 4; ++mf)
#pragma unroll
      for (int nf = 0; nf < 4; ++nf)
        acc[mf][nf] = __builtin_amdgcn_mfma_f32_16x16x32_bf16(af[ks][mf], bg[ks][nf], acc[mf][nf], 0, 0, 0);

  const int rr = (lane >> 4) * 4;
#pragma unroll
  for (int mf = 0; mf < 4; ++mf)
#pragma unroll
    for (int nf = 0; nf < 4; ++nf) {
      int col = nh * 256 + wid * 64 + nf * 16 + lr;
#pragma unroll
      for (int r = 0; r < 4; ++r) {
        int row = m0 + mf * 16 + rr + r;
        R[((size_t)row * 8 + h) * 512 + col] = f2b(acc[mf][nf][r]);
      }
    }
}

// ---------------------------------------------------------------------------
// Fused attention: WAVE-PER-TOKEN, zero barriers. Block = 4 waves = 4 tokens.
// Phase 1: lane holds R[h][lane*8..+8] (64 f32 regs). Per w: one coalesced
//   2KB key-row load, 64 FMA, two-stage reduce (3-step butterfly over 8 heads,
//   cndmask-tree select of s[lane&7], 3-step single-value butterfly) ->
//   score(h=lane&7,w) replicated; lanes 0-7 write to wave-private LDS.
// Mask: single __ballot -> SGPR mbits; all-masked handled via ss guard.
// Softmax: all-lane redundant per-head (broadcast LDS reads, conflict-free),
//   fully parallel; lanes 0-7 write back e and inv.
// Phase 2: per w one coalesced 2KB value-row load + 8 broadcast LDS reads of
//   a[h][w] + 64 FMA into statically-indexed gg[8][8].
// Intra-wave LDS ordering is program-order (lgkmcnt) -> NO __syncthreads.
// ---------------------------------------------------------------------------
__global__ __launch_bounds__(256)
void attn_fused(const float* __restrict__ key, const float* __restrict__ value,
                const ushort* __restrict__ R, const int* __restrict__ mask,
                ushort* __restrict__ g, float* __restrict__ asum)
{
  __shared__ float lsc[4][8][36];   // per-wave score/prob rows
  __shared__ float linv[4][8];

  const int tid  = threadIdx.x;
  const int lane = tid & 63;
  const int wv   = tid >> 6;
  const int bt   = blockIdx.x * 4 + wv;

  // mask ballot -> wave-uniform 33-bit mask
  int mreg = 0;
  if (lane < W_) mreg = mask[(size_t)bt * W_ + lane];
  unsigned long long mbits = __ballot(mreg != 0);

  // unpack R[bt]: lane l -> R[h][l*8..+8] as f32 (64 regs)
  float Rf[8][8];
  {
    const ushort* Rb = R + (size_t)bt * 4096 + lane * 8;
#pragma unroll
    for (int h = 0; h < 8; ++h) {
      short8 rv = *(const short8*)(Rb + h * 512);
#pragma unroll
      for (int j = 0; j < 8; ++j) Rf[h][j] = b2f((ushort)rv[j]);
    }
  }

  // ---- phase 1: scores ----
  const float* kb = key + (size_t)bt * (W_ * 512) + lane * 8;
#pragma unroll 2
  for (int w = 0; w < W_; ++w) {
    float4 k0 = *(const float4*)(kb + (size_t)w * 512);
    float4 k1 = *(const float4*)(kb + (size_t)w * 512 + 4);
    float s[8];
#pragma unroll
    for (int h = 0; h < 8; ++h)
      s[h] = k0.x * Rf[h][0] + k0.y * Rf[h][1] + k0.z * Rf[h][2] + k0.w * Rf[h][3]
           + k1.x * Rf[h][4] + k1.y * Rf[h][5] + k1.z * Rf[h][6] + k1.w * Rf[h][7];
    // stage 1: reduce within 8-lane groups, all 8 heads (ILP=8)
#pragma unroll
    for (int m = 1; m <= 4; m <<= 1)
#pragma unroll
      for (int h = 0; h < 8; ++h) s[h] += __shfl_xor(s[h], m, 64);
    // static select t = s[lane&7]
    float ta = (lane & 1) ? s[1] : s[0];
    float tb = (lane & 1) ? s[3] : s[2];
    float tc = (lane & 1) ? s[5] : s[4];
    float td = (lane & 1) ? s[7] : s[6];
    float ua = (lane & 2) ? tb : ta;
    float ub = (lane & 2) ? td : tc;
    float t  = (lane & 4) ? ub : ua;
    // stage 2: reduce across the 8 groups
    t += __shfl_xor(t, 8, 64);
    t += __shfl_xor(t, 16, 64);
    t += __shfl_xor(t, 32, 64);
    // mask (wave-uniform scalar test)
    t = ((mbits >> w) & 1ull) ? t : -3.0e38f;
    if (lane < 8) lsc[wv][lane][w] = t;
  }

  // ---- softmax (all lanes, redundant per head lane&7; no barrier) ----
  const int hh = lane & 7;
  float mx = -3.4028234663852886e38f;
  for (int w = 0; w < W_; ++w) mx = fmaxf(mx, lsc[wv][hh][w]);
  float ss = 0.f;
  for (int w = 0; w < W_; ++w) {
    float e = ((mbits >> w) & 1ull) ? __expf(lsc[wv][hh][w] - mx) : 0.f;
    ss += e;
    if (lane < 8) lsc[wv][lane][w] = e;
  }
  float inv = (ss > 0.5f) ? 1.f / ss : 0.f;   // ss >= 1 whenever any unmasked
  if (lane < 8) {
    linv[wv][lane] = inv;
    asum[(size_t)bt * H_ + lane] = (mbits != 0ull) ? 1.f : 0.f;
  }

  // ---- phase 2: value aggregation, lane owns cols lane*8..+7 ----
  float gg[8][8];
#pragma unroll
  for (int h = 0; h < 8; ++h)
#pragma unroll
    for (int c = 0; c < 8; ++c) gg[h][c] = 0.f;

  const float* vb = value + (size_t)bt * (W_ * 512) + lane * 8;
#pragma unroll 2
  for (int w = 0; w < W_; ++w) {
    float4 v0 = *(const float4*)(vb + (size_t)w * 512);
    float4 v1 = *(const float4*)(vb + (size_t)w * 512 + 4);
    float a[8];
#pragma unroll
    for (int h = 0; h < 8; ++h) a[h] = lsc[wv][h][w];   // broadcast reads
#pragma unroll
    for (int h = 0; h < 8; ++h) {
      gg[h][0] += a[h] * v0.x; gg[h][1] += a[h] * v0.y;
      gg[h][2] += a[h] * v0.z; gg[h][3] += a[h] * v0.w;
      gg[h][4] += a[h] * v1.x; gg[h][5] += a[h] * v1.y;
      gg[h][6] += a[h] * v1.z; gg[h][7] += a[h] * v1.w;
    }
  }

  // ---- epilogue: normalize + pack bf16 + store ----
  ushort* gb = g + (size_t)bt * 4096 + lane * 8;
#pragma unroll
  for (int h = 0; h < 8; ++h) {
    float iv = linv[wv][h];
    short8 o;
#pragma unroll
    for (int c = 0; c < 8; ++c) o[c] = (short)f2b(gg[h][c] * iv);
    *(short8*)(gb + h * 512) = o;
  }
}

// ---------------------------------------------------------------------------
// x-proj: x[bt, h*64+d] = sum_f g[bt,h,f]*Wv[f,h*64+d] + asum[bt,h]*bv[h*64+d]
// ---------------------------------------------------------------------------
__global__ __launch_bounds__(256, 2)
void x_proj(const ushort* __restrict__ g, const ushort* __restrict__ WtV,
            const float* __restrict__ bv, const float* __restrict__ asum,
            ushort* __restrict__ x)
{
  const int tid  = threadIdx.x;
  const int lane = tid & 63;
  const int wid  = tid >> 6;
  const int lr   = lane & 15;
  const int l8   = (lane >> 4) * 8;
  const int h    = blockIdx.y;
  const int m0   = blockIdx.x * 256 + wid * 64;
  const int ntb  = h * 4;

  f32x4 acc[4][4];
#pragma unroll
  for (int i = 0; i < 4; ++i)
#pragma unroll
    for (int j = 0; j < 4; ++j) acc[i][j] = {0.f, 0.f, 0.f, 0.f};

  short8 a0[4], a1[4], b0[4], b1[4];

  auto issue = [&](int ks, short8 (&A)[4], short8 (&Bq)[4]) {
#pragma unroll
    for (int mf = 0; mf < 4; ++mf)
      A[mf] = *(const short8*)(g + ((size_t)(m0 + mf * 16 + lr) * 8 + h) * 512 + ks * 32 + l8);
#pragma unroll
    for (int nf = 0; nf < 4; ++nf)
      Bq[nf] = *(const short8*)(WtV + ((size_t)((ntb + nf) * 16 + ks) * 64 + lane) * 8);
  };
  auto step = [&](short8 (&A)[4], short8 (&Bq)[4]) {
#pragma unroll
    for (int mf = 0; mf < 4; ++mf)
#pragma unroll
      for (int nf = 0; nf < 4; ++nf)
        acc[mf][nf] = __builtin_amdgcn_mfma_f32_16x16x32_bf16(A[mf], Bq[nf], acc[mf][nf], 0, 0, 0);
  };

  issue(0, a0, b0);
  issue(1, a1, b1);
#pragma unroll 1
  for (int ks = 0; ks < 16; ks += 2) {
    step(a0, b0);
    if (ks + 2 < 16) issue(ks + 2, a0, b0);
    step(a1, b1);
    if (ks + 3 < 16) issue(ks + 3, a1, b1);
  }

  float bvv[4];
#pragma unroll
  for (int nf = 0; nf < 4; ++nf)
    bvv[nf] = bv[h * 64 + nf * 16 + lr];

  const int rr = (lane >> 4) * 4;
#pragma unroll
  for (int mf = 0; mf < 4; ++mf)
#pragma unroll
    for (int nf = 0; nf < 4; ++nf) {
      int col = h * 64 + nf * 16 + lr;
#pragma unroll
      for (int r = 0; r < 4; ++r) {
        int row = m0 + mf * 16 + rr + r;
        float val = acc[mf][nf][r] + asum[(size_t)row * 8 + h] * bvv[nf];
        x[(size_t)row * 512 + col] = f2b(val);
      }
    }
}

// ---------------------------------------------------------------------------
extern "C" void kernel_launch(void* const* d_in, const int* in_sizes, int n_in,
                              void* d_out, int out_size, void* d_ws, size_t ws_size,
                              hipStream_t stream)
{
  const float* query = (const float*)d_in[0];
  const float* key   = (const float*)d_in[1];
  const float* value = (const float*)d_in[2];
  const int*   mask  = (const int*)d_in[3];
  const float* Wq    = (const float*)d_in[4];
  const float* bq    = (const float*)d_in[5];
  const float* Wk    = (const float*)d_in[6];
  const float* bk    = (const float*)d_in[7];   // cancels in softmax (unused)
  const float* Wv    = (const float*)d_in[8];
  const float* bv    = (const float*)d_in[9];
  const float* Wo    = (const float*)d_in[10];
  const float* bo    = (const float*)d_in[11];
  (void)bk;

  char* ws = (char*)d_ws;
  ushort* Wt   = (ushort*)ws;                   // 4 tables x 512 KB = 2 MB
  ushort* WtQ  = Wt;
  ushort* WkR  = Wt + 262144;
  ushort* WtV  = Wt + 524288;
  ushort* WtO  = Wt + 786432;
  ushort* qws  = (ushort*)(ws + (size_t)2  * 1024 * 1024);  //  4 MB bf16 q
  ushort* Rws  = (ushort*)(ws + (size_t)6  * 1024 * 1024);  // 32 MB bf16 R
  ushort* gws  = (ushort*)(ws + (size_t)38 * 1024 * 1024);  // 32 MB bf16 g
  float*  asum = (float*) (ws + (size_t)70 * 1024 * 1024);  // 128 KB
  ushort* xws  = (ushort*)(ws + (size_t)71 * 1024 * 1024);  //  4 MB bf16 x

  // 1. weight tables
  convert_w<<<dim3(1024, 4), 256, 0, stream>>>(Wq, Wk, Wv, Wo, Wt);

  // 2. q = (query@Wq + bq) / 8   (scale folded; bf16 out)
  gemm_pipe<true, false><<<dim3(128, 1), 256, 0, stream>>>(query, WtQ, bq, qws, 0.125f);

  // 3. R[bt,h,f] = sum_d Wk[f,hd] * q[bt,hd]
  r_gemm<<<dim3(128, 8), 256, 0, stream>>>(qws, WkR, Rws);

  // 4. fused scores+softmax+value-aggregate (wave-per-token, barrier-free)
  attn_fused<<<dim3(B_ * T_ / 4, 1), 256, 0, stream>>>(key, value, Rws, mask, gws, asum);

  // 5. x[bt,hd] = g_h @ Wv_h + asum*bv
  x_proj<<<dim3(16, 8), 256, 0, stream>>>(gws, WtV, bv, asum, xws);

  // 6. out = x@Wo + bo  (f32 out)
  gemm_pipe<false, true><<<dim3(128, 1), 256, 0, stream>>>(xws, WtO, bo, d_out, 1.0f);
}

// Round 10
// 180.297 us; speedup vs baseline: 1.1565x; 1.1565x over previous
//
#include <hip/hip_runtime.h>
#include <hip/hip_bf16.h>
#include <cstdint>

// Problem constants
#define B_ 4
#define T_ 1024
#define W_ 33
#define F_ 512
#define H_ 8
#define DK_ 64

typedef __attribute__((ext_vector_type(8))) short short8;
typedef __attribute__((ext_vector_type(4))) float f32x4;

__device__ __forceinline__ float b2f(ushort u) {
  return __uint_as_float(((uint32_t)u) << 16);
}
__device__ __forceinline__ ushort f2b(float f) {
  union { __hip_bfloat16 b; ushort u; } cv;
  cv.b = __float2bfloat16(f);
  return cv.u;
}

// ---------------------------------------------------------------------------
// Weight convert.
// which=0,2,3 (Wq,Wv,Wo): orig MFMA-frag order for B[n,k]=W[k,n]:
//   dst[((nt*16+kc)*64+l)*8+e] = W[k,n], n=nt*16+(l&15), k=kc*32+(l>>4)*8+e
// which=1 (Wk): per-head TRANSPOSED table for R-GEMM, B[n=f,k=d]=Wk[f,h*64+d]:
//   dst[(((h*32+ntf)*2+kc)*64+l)*8+e] = Wk[ntf*16+(l&15), h*64+kc*32+(l>>4)*8+e]
// ---------------------------------------------------------------------------
__global__ void convert_w(const float* __restrict__ Wq, const float* __restrict__ Wk,
                          const float* __restrict__ Wv, const float* __restrict__ Wo,
                          ushort* __restrict__ out)
{
  int which = blockIdx.y;
  const float* src = (which == 0) ? Wq : (which == 1) ? Wk : (which == 2) ? Wv : Wo;
  ushort* dst = out + (size_t)which * 262144;
  int idx = blockIdx.x * 256 + threadIdx.x;     // 0 .. 262143
  int e = idx & 7;
  int l = (idx >> 3) & 63;
  float v;
  if (which == 1) {
    int kc  = (idx >> 9) & 1;
    int ntf = (idx >> 10) & 31;
    int h   = idx >> 15;
    v = src[(size_t)(ntf * 16 + (l & 15)) * 512 + h * 64 + kc * 32 + ((l >> 4) << 3) + e];
  } else {
    int kc = (idx >> 9) & 15;
    int nt = idx >> 13;
    int k = kc * 32 + ((l >> 4) << 3) + e;
    int n = (nt << 4) + (l & 15);
    v = src[(size_t)k * 512 + n];
  }
  dst[idx] = f2b(v);
}

// ---------------------------------------------------------------------------
// Pipelined GEMM (q-proj / O-proj): C[M x 512] = (A[M x 512] @ W + bias)*scale
// ---------------------------------------------------------------------------
template<bool A_F32, bool OUT_F32>
__global__ __launch_bounds__(256, 2)
void gemm_pipe(const void* __restrict__ Ap, const ushort* __restrict__ Bf,
               const float* __restrict__ bias, void* __restrict__ Cp, float scale)
{
  __shared__ ushort lA[3][128 * 64];

  const int tid  = threadIdx.x;
  const int lane = tid & 63;
  const int wid  = tid >> 6;
  const int wr   = wid >> 1, wc = wid & 1;
  const int lrow = lane & 15;
  const int lk8  = (lane >> 4) * 8;

  int nwg  = gridDim.x;
  int xcd  = blockIdx.x & 7;
  int slot = blockIdx.x >> 3;
  int q8   = nwg >> 3, r8 = nwg & 7;
  int base = (xcd < r8) ? xcd * (q8 + 1) : r8 * (q8 + 1) + (xcd - r8) * q8;
  int L    = base + slot;
  int bm   = L >> 2;
  int bn   = L & 3;

  int lb_[4];
  size_t asrc_[4];
#pragma unroll
  for (int p = 0; p < 4; ++p) {
    int c   = p * 256 + tid;
    int row = c >> 3;
    int kc  = (c & 7) * 8;
    lb_[p]  = (row * 128 + kc * 2) ^ ((row & 7) << 4);
    asrc_[p] = (size_t)(bm * 128 + row) * 512 + kc;
  }

  const int ntb = bn * 8 + wc * 4;

  float4 P0a0[4], P0a1[4], P1a0[4], P1a1[4];
  short8 P0r[4], P1r[4];
  short8 Q0[8], Q1[8];

  auto issueA = [&](int ks, float4 (&d0)[4], float4 (&d1)[4], short8 (&dr)[4]) {
#pragma unroll
    for (int p = 0; p < 4; ++p) {
      if (A_F32) {
        const float* src = (const float*)Ap + asrc_[p] + ks * 64;
        d0[p] = *(const float4*)src;
        d1[p] = *(const float4*)(src + 4);
      } else {
        dr[p] = *(const short8*)((const ushort*)Ap + asrc_[p] + ks * 64);
      }
    }
  };
  auto lwriteA = [&](int buf, float4 (&d0)[4], float4 (&d1)[4], short8 (&dr)[4]) {
#pragma unroll
    for (int p = 0; p < 4; ++p) {
      short8 hv;
      if (A_F32) {
        hv[0] = (short)f2b(d0[p].x); hv[1] = (short)f2b(d0[p].y);
        hv[2] = (short)f2b(d0[p].z); hv[3] = (short)f2b(d0[p].w);
        hv[4] = (short)f2b(d1[p].x); hv[5] = (short)f2b(d1[p].y);
        hv[6] = (short)f2b(d1[p].z); hv[7] = (short)f2b(d1[p].w);
      } else {
        hv = dr[p];
      }
      *(short8*)((char*)lA[buf] + lb_[p]) = hv;
    }
  };
  auto loadB = [&](int ks, short8 (&dq)[8]) {
#pragma unroll
    for (int kk = 0; kk < 2; ++kk)
#pragma unroll
      for (int nf = 0; nf < 4; ++nf)
        dq[kk * 4 + nf] = *(const short8*)(Bf +
            (((size_t)(ntb + nf) * 16 + ks * 2 + kk) * 64 + lane) * 8);
  };

  f32x4 acc[4][4];
#pragma unroll
  for (int i = 0; i < 4; ++i)
#pragma unroll
    for (int j = 0; j < 4; ++j) acc[i][j] = {0.f, 0.f, 0.f, 0.f};

  auto computeStep = [&](int buf, short8 (&dq)[8]) {
#pragma unroll
    for (int kk = 0; kk < 2; ++kk) {
      short8 af[4];
#pragma unroll
      for (int mf = 0; mf < 4; ++mf) {
        int row = wr * 64 + mf * 16 + lrow;
        int off = (row * 128 + (kk * 32 + lk8) * 2) ^ ((row & 7) << 4);
        af[mf] = *(const short8*)((const char*)lA[buf] + off);
      }
#pragma unroll
      for (int mf = 0; mf < 4; ++mf)
#pragma unroll
        for (int nf = 0; nf < 4; ++nf)
          acc[mf][nf] = __builtin_amdgcn_mfma_f32_16x16x32_bf16(af[mf], dq[kk * 4 + nf], acc[mf][nf], 0, 0, 0);
    }
  };

  issueA(0, P0a0, P0a1, P0r);
  issueA(1, P1a0, P1a1, P1r);
  loadB(0, Q0);
  lwriteA(0, P0a0, P0a1, P0r);
  __syncthreads();

#define GSTEP(T, PWa0, PWa1, PWr, PIa0, PIa1, PIr, QW, QR)                    \
  {                                                                           \
    if ((T) + 1 < 8) lwriteA(((T) + 1) % 3, PWa0, PWa1, PWr);                 \
    if ((T) + 2 < 8) issueA((T) + 2, PIa0, PIa1, PIr);                        \
    if ((T) + 1 < 8) loadB((T) + 1, QW);                                      \
    computeStep((T) % 3, QR);                                                 \
    if ((T) < 7) __syncthreads();                                             \
  }

  GSTEP(0, P1a0, P1a1, P1r, P0a0, P0a1, P0r, Q1, Q0)
  GSTEP(1, P0a0, P0a1, P0r, P1a0, P1a1, P1r, Q0, Q1)
  GSTEP(2, P1a0, P1a1, P1r, P0a0, P0a1, P0r, Q1, Q0)
  GSTEP(3, P0a0, P0a1, P0r, P1a0, P1a1, P1r, Q0, Q1)
  GSTEP(4, P1a0, P1a1, P1r, P0a0, P0a1, P0r, Q1, Q0)
  GSTEP(5, P0a0, P0a1, P0r, P1a0, P1a1, P1r, Q0, Q1)
  GSTEP(6, P1a0, P1a1, P1r, P0a0, P0a1, P0r, Q1, Q0)
  GSTEP(7, P0a0, P0a1, P0r, P1a0, P1a1, P1r, Q0, Q1)
#undef GSTEP

  float bs[4];
#pragma unroll
  for (int nf = 0; nf < 4; ++nf)
    bs[nf] = bias[bn * 128 + wc * 64 + nf * 16 + lrow];

  const int r0 = (lane >> 4) * 4;
#pragma unroll
  for (int mf = 0; mf < 4; ++mf) {
#pragma unroll
    for (int nf = 0; nf < 4; ++nf) {
      int gcol = bn * 128 + wc * 64 + nf * 16 + lrow;
#pragma unroll
      for (int r = 0; r < 4; ++r) {
        int grow = bm * 128 + wr * 64 + mf * 16 + r0 + r;
        float val = (acc[mf][nf][r] + bs[nf]) * scale;
        if (OUT_F32) ((float*)Cp)[(size_t)grow * 512 + gcol] = val;
        else         ((ushort*)Cp)[(size_t)grow * 512 + gcol] = f2b(val);
      }
    }
  }
}

// ---------------------------------------------------------------------------
// R-GEMM: R[bt,h,f] = sum_d q[bt,h*64+d] * Wk[f,h*64+d]   (q already /8)
// ---------------------------------------------------------------------------
__global__ __launch_bounds__(256, 4)
void r_gemm(const ushort* __restrict__ q, const ushort* __restrict__ WkR,
            ushort* __restrict__ R)
{
  const int tid  = threadIdx.x;
  const int lane = tid & 63;
  const int wid  = tid >> 6;
  const int lr   = lane & 15;
  const int l8   = (lane >> 4) * 8;
  const int mg   = blockIdx.x >> 1;
  const int nh   = blockIdx.x & 1;
  const int h    = blockIdx.y;
  const int m0   = mg * 64;
  const int ntb  = nh * 16 + wid * 4;

  short8 af[2][4], bg[2][4];
#pragma unroll
  for (int ks = 0; ks < 2; ++ks)
#pragma unroll
    for (int mf = 0; mf < 4; ++mf)
      af[ks][mf] = *(const short8*)(q + (size_t)(m0 + mf * 16 + lr) * 512 + h * 64 + ks * 32 + l8);
#pragma unroll
  for (int ks = 0; ks < 2; ++ks)
#pragma unroll
    for (int nf = 0; nf < 4; ++nf)
      bg[ks][nf] = *(const short8*)(WkR + ((size_t)((h * 32 + ntb + nf) * 2 + ks) * 64 + lane) * 8);

  f32x4 acc[4][4];
#pragma unroll
  for (int i = 0; i < 4; ++i)
#pragma unroll
    for (int j = 0; j < 4; ++j) acc[i][j] = {0.f, 0.f, 0.f, 0.f};

#pragma unroll
  for (int ks = 0; ks < 2; ++ks)
#pragma unroll
    for (int mf = 0; mf < 4; ++mf)
#pragma unroll
      for (int nf = 0; nf < 4; ++nf)
        acc[mf][nf] = __builtin_amdgcn_mfma_f32_16x16x32_bf16(af[ks][mf], bg[ks][nf], acc[mf][nf], 0, 0, 0);

  const int rr = (lane >> 4) * 4;
#pragma unroll
  for (int mf = 0; mf < 4; ++mf)
#pragma unroll
    for (int nf = 0; nf < 4; ++nf) {
      int col = nh * 256 + wid * 64 + nf * 16 + lr;
#pragma unroll
      for (int r = 0; r < 4; ++r) {
        int row = m0 + mf * 16 + rr + r;
        R[((size_t)row * 8 + h) * 512 + col] = f2b(acc[mf][nf][r]);
      }
    }
}

// ---------------------------------------------------------------------------
// Fused attention v3: BLOCK-PER-TOKEN (grid 4096), deep register prefetch.
// Phase 1: wave wv owns key rows {wv+4j, j=0..7} (+ row 32 for wv==0), ALL
//   loaded up-front into kA[4]/kB[5] (in-flight while computing). Per row:
//   64 FMA vs in-reg R, two-stage reduce (3-step ILP-8 butterfly, static
//   cndmask select, 3-step chain), lanes 0-7 write score to LDS.
// Softmax: all-256-thread redundant per head (tid&7) off broadcast LDS reads;
//   the 264 probability entries written by a +=256 strided loop (256 = 0 mod 8
//   keeps the head association of each thread's mx). Mask via __ballot.
// Phase 2: value prefetched into 3x8-row register buffers ISSUED BEFORE the
//   softmax pass (its ~600cy covers the latency); thread owns 2 columns,
//   statically unrolled consume, 16 accum regs. Two barriers total.
// ---------------------------------------------------------------------------
__global__ __launch_bounds__(256, 2)
void attn_fused(const float* __restrict__ key, const float* __restrict__ value,
                const ushort* __restrict__ R, const int* __restrict__ mask,
                ushort* __restrict__ g, float* __restrict__ asum)
{
  __shared__ float sc[H_][W_ + 3];   // raw scores
  __shared__ float la[H_][W_ + 3];   // probabilities
  __shared__ float linv[H_];

  const int tid  = threadIdx.x;
  const int lane = tid & 63;
  const int wv   = tid >> 6;
  const int bt   = blockIdx.x;

  // mask ballot -> wave-uniform 33-bit mask (identical in all 4 waves)
  int mreg = 0;
  if (lane < W_) mreg = mask[(size_t)bt * W_ + lane];
  unsigned long long mbits = __ballot(mreg != 0);

  // unpack R[bt]: lane l -> R[h][l*8..+8] as f32 (64 regs)
  float Rf[8][8];
  {
    const ushort* Rb = R + (size_t)bt * 4096 + lane * 8;
#pragma unroll
    for (int h = 0; h < 8; ++h) {
      short8 rv = *(const short8*)(Rb + h * 512);
#pragma unroll
      for (int j = 0; j < 8; ++j) Rf[h][j] = b2f((ushort)rv[j]);
    }
  }

  // ---- phase 1: all key-row loads issued up-front ----
  const float* kb = key + (size_t)bt * (W_ * 512) + lane * 8;
  float kA[4][8], kB[5][8];
#pragma unroll
  for (int jj = 0; jj < 4; ++jj) {
    int w = wv + jj * 4;
    float4 a = *(const float4*)(kb + (size_t)w * 512);
    float4 b = *(const float4*)(kb + (size_t)w * 512 + 4);
    kA[jj][0] = a.x; kA[jj][1] = a.y; kA[jj][2] = a.z; kA[jj][3] = a.w;
    kA[jj][4] = b.x; kA[jj][5] = b.y; kA[jj][6] = b.z; kA[jj][7] = b.w;
  }
#pragma unroll
  for (int jj = 0; jj < 4; ++jj) {
    int w = wv + 16 + jj * 4;
    float4 a = *(const float4*)(kb + (size_t)w * 512);
    float4 b = *(const float4*)(kb + (size_t)w * 512 + 4);
    kB[jj][0] = a.x; kB[jj][1] = a.y; kB[jj][2] = a.z; kB[jj][3] = a.w;
    kB[jj][4] = b.x; kB[jj][5] = b.y; kB[jj][6] = b.z; kB[jj][7] = b.w;
  }
  if (wv == 0) {                      // wave-uniform branch
    float4 a = *(const float4*)(kb + (size_t)32 * 512);
    float4 b = *(const float4*)(kb + (size_t)32 * 512 + 4);
    kB[4][0] = a.x; kB[4][1] = a.y; kB[4][2] = a.z; kB[4][3] = a.w;
    kB[4][4] = b.x; kB[4][5] = b.y; kB[4][6] = b.z; kB[4][7] = b.w;
  }

  auto scoreRow = [&](const float (&kr)[8], int w) {
    float s[8];
#pragma unroll
    for (int h = 0; h < 8; ++h)
      s[h] = kr[0] * Rf[h][0] + kr[1] * Rf[h][1] + kr[2] * Rf[h][2] + kr[3] * Rf[h][3]
           + kr[4] * Rf[h][4] + kr[5] * Rf[h][5] + kr[6] * Rf[h][6] + kr[7] * Rf[h][7];
#pragma unroll
    for (int m = 1; m <= 4; m <<= 1)
#pragma unroll
      for (int h = 0; h < 8; ++h) s[h] += __shfl_xor(s[h], m, 64);
    float ta = (lane & 1) ? s[1] : s[0];
    float tb = (lane & 1) ? s[3] : s[2];
    float tc = (lane & 1) ? s[5] : s[4];
    float td = (lane & 1) ? s[7] : s[6];
    float ua = (lane & 2) ? tb : ta;
    float ub = (lane & 2) ? td : tc;
    float t  = (lane & 4) ? ub : ua;
    t += __shfl_xor(t, 8, 64);
    t += __shfl_xor(t, 16, 64);
    t += __shfl_xor(t, 32, 64);
    t = ((mbits >> w) & 1ull) ? t : -3.0e38f;
    if (lane < 8) sc[lane][w] = t;
  };

#pragma unroll
  for (int jj = 0; jj < 4; ++jj) scoreRow(kA[jj], wv + jj * 4);
#pragma unroll
  for (int jj = 0; jj < 4; ++jj) scoreRow(kB[jj], wv + 16 + jj * 4);
  if (wv == 0) scoreRow(kB[4], 32);
  __syncthreads();

  // ---- value prefetch (issued BEFORE softmax; latency hides under it) ----
  const float* vb = value + (size_t)bt * (W_ * 512) + tid * 2;
  float2 vA[8], vB[8], vC[8];
#pragma unroll
  for (int i = 0; i < 8; ++i) vA[i] = *(const float2*)(vb + (size_t)i * 512);
#pragma unroll
  for (int i = 0; i < 8; ++i) vB[i] = *(const float2*)(vb + (size_t)(8 + i) * 512);
#pragma unroll
  for (int i = 0; i < 8; ++i) vC[i] = *(const float2*)(vb + (size_t)(16 + i) * 512);

  // ---- softmax: all threads redundant for head tid&7 ----
  const int hh = tid & 7;
  float mx = -3.4028234663852886e38f;
#pragma unroll
  for (int w = 0; w < W_; ++w) mx = fmaxf(mx, sc[hh][w]);
  float ss = 0.f;
#pragma unroll
  for (int w = 0; w < W_; ++w)
    ss += ((mbits >> w) & 1ull) ? __expf(sc[hh][w] - mx) : 0.f;

  // probabilities: 264 entries; t and t+256 share t&7 (256 % 8 == 0), so this
  // thread's mx (for head hh) is valid for both of its entries.
  for (int t = tid; t < H_ * W_ + (264 - H_ * W_); t += 256) {
    if (t < 264) {
      int w = t >> 3;
      la[hh][w] = ((mbits >> w) & 1ull) ? __expf(sc[hh][w] - mx) : 0.f;
    }
  }
  if (tid < H_) {
    linv[tid] = (ss > 0.5f) ? 1.f / ss : 0.f;
    asum[(size_t)bt * H_ + tid] = (mbits != 0ull) ? 1.f : 0.f;
  }
  __syncthreads();

  // ---- phase 2: value aggregation; thread owns cols 2t, 2t+1 ----
  float gg0[8], gg1[8];
#pragma unroll
  for (int h = 0; h < 8; ++h) { gg0[h] = 0.f; gg1[h] = 0.f; }

  auto consume = [&](float2 v, int w) {
#pragma unroll
    for (int h = 0; h < 8; ++h) {
      float a = la[h][w];            // broadcast LDS read
      gg0[h] += a * v.x;
      gg1[h] += a * v.y;
    }
  };

#pragma unroll
  for (int i = 0; i < 8; ++i) consume(vA[i], i);          // w 0..7
#pragma unroll
  for (int i = 0; i < 8; ++i) vA[i] = *(const float2*)(vb + (size_t)(24 + i) * 512);
#pragma unroll
  for (int i = 0; i < 8; ++i) consume(vB[i], 8 + i);      // w 8..15
  float2 vL = *(const float2*)(vb + (size_t)32 * 512);
#pragma unroll
  for (int i = 0; i < 8; ++i) consume(vC[i], 16 + i);     // w 16..23
#pragma unroll
  for (int i = 0; i < 8; ++i) consume(vA[i], 24 + i);     // w 24..31
  consume(vL, 32);

  // ---- epilogue: normalize + pack bf16 + store ----
  ushort* gb = g + (size_t)bt * 4096 + tid * 2;
#pragma unroll
  for (int h = 0; h < 8; ++h) {
    float iv = linv[h];
    ushort2 pk;
    pk.x = f2b(gg0[h] * iv);
    pk.y = f2b(gg1[h] * iv);
    *(ushort2*)(gb + h * 512) = pk;
  }
}

// ---------------------------------------------------------------------------
// x-proj: x[bt, h*64+d] = sum_f g[bt,h,f]*Wv[f,h*64+d] + asum[bt,h]*bv[h*64+d]
// ---------------------------------------------------------------------------
__global__ __launch_bounds__(256, 2)
void x_proj(const ushort* __restrict__ g, const ushort* __restrict__ WtV,
            const float* __restrict__ bv, const float* __restrict__ asum,
            ushort* __restrict__ x)
{
  const int tid  = threadIdx.x;
  const int lane = tid & 63;
  const int wid  = tid >> 6;
  const int lr   = lane & 15;
  const int l8   = (lane >> 4) * 8;
  const int h    = blockIdx.y;
  const int m0   = blockIdx.x * 256 + wid * 64;
  const int ntb  = h * 4;

  f32x4 acc[4][4];
#pragma unroll
  for (int i = 0; i < 4; ++i)
#pragma unroll
    for (int j = 0; j < 4; ++j) acc[i][j] = {0.f, 0.f, 0.f, 0.f};

  short8 a0[4], a1[4], b0[4], b1[4];

  auto issue = [&](int ks, short8 (&A)[4], short8 (&Bq)[4]) {
#pragma unroll
    for (int mf = 0; mf < 4; ++mf)
      A[mf] = *(const short8*)(g + ((size_t)(m0 + mf * 16 + lr) * 8 + h) * 512 + ks * 32 + l8);
#pragma unroll
    for (int nf = 0; nf < 4; ++nf)
      Bq[nf] = *(const short8*)(WtV + ((size_t)((ntb + nf) * 16 + ks) * 64 + lane) * 8);
  };
  auto step = [&](short8 (&A)[4], short8 (&Bq)[4]) {
#pragma unroll
    for (int mf = 0; mf < 4; ++mf)
#pragma unroll
      for (int nf = 0; nf < 4; ++nf)
        acc[mf][nf] = __builtin_amdgcn_mfma_f32_16x16x32_bf16(A[mf], Bq[nf], acc[mf][nf], 0, 0, 0);
  };

  issue(0, a0, b0);
  issue(1, a1, b1);
#pragma unroll 1
  for (int ks = 0; ks < 16; ks += 2) {
    step(a0, b0);
    if (ks + 2 < 16) issue(ks + 2, a0, b0);
    step(a1, b1);
    if (ks + 3 < 16) issue(ks + 3, a1, b1);
  }

  float bvv[4];
#pragma unroll
  for (int nf = 0; nf < 4; ++nf)
    bvv[nf] = bv[h * 64 + nf * 16 + lr];

  const int rr = (lane >> 4) * 4;
#pragma unroll
  for (int mf = 0; mf < 4; ++mf)
#pragma unroll
    for (int nf = 0; nf < 4; ++nf) {
      int col = h * 64 + nf * 16 + lr;
#pragma unroll
      for (int r = 0; r < 4; ++r) {
        int row = m0 + mf * 16 + rr + r;
        float val = acc[mf][nf][r] + asum[(size_t)row * 8 + h] * bvv[nf];
        x[(size_t)row * 512 + col] = f2b(val);
      }
    }
}

// ---------------------------------------------------------------------------
extern "C" void kernel_launch(void* const* d_in, const int* in_sizes, int n_in,
                              void* d_out, int out_size, void* d_ws, size_t ws_size,
                              hipStream_t stream)
{
  const float* query = (const float*)d_in[0];
  const float* key   = (const float*)d_in[1];
  const float* value = (const float*)d_in[2];
  const int*   mask  = (const int*)d_in[3];
  const float* Wq    = (const float*)d_in[4];
  const float* bq    = (const float*)d_in[5];
  const float* Wk    = (const float*)d_in[6];
  const float* bk    = (const float*)d_in[7];   // cancels in softmax (unused)
  const float* Wv    = (const float*)d_in[8];
  const float* bv    = (const float*)d_in[9];
  const float* Wo    = (const float*)d_in[10];
  const float* bo    = (const float*)d_in[11];
  (void)bk;

  char* ws = (char*)d_ws;
  ushort* Wt   = (ushort*)ws;                   // 4 tables x 512 KB = 2 MB
  ushort* WtQ  = Wt;
  ushort* WkR  = Wt + 262144;
  ushort* WtV  = Wt + 524288;
  ushort* WtO  = Wt + 786432;
  ushort* qws  = (ushort*)(ws + (size_t)2  * 1024 * 1024);  //  4 MB bf16 q
  ushort* Rws  = (ushort*)(ws + (size_t)6  * 1024 * 1024);  // 32 MB bf16 R
  ushort* gws  = (ushort*)(ws + (size_t)38 * 1024 * 1024);  // 32 MB bf16 g
  float*  asum = (float*) (ws + (size_t)70 * 1024 * 1024);  // 128 KB
  ushort* xws  = (ushort*)(ws + (size_t)71 * 1024 * 1024);  //  4 MB bf16 x

  // 1. weight tables
  convert_w<<<dim3(1024, 4), 256, 0, stream>>>(Wq, Wk, Wv, Wo, Wt);

  // 2. q = (query@Wq + bq) / 8   (scale folded; bf16 out)
  gemm_pipe<true, false><<<dim3(128, 1), 256, 0, stream>>>(query, WtQ, bq, qws, 0.125f);

  // 3. R[bt,h,f] = sum_d Wk[f,hd] * q[bt,hd]
  r_gemm<<<dim3(128, 8), 256, 0, stream>>>(qws, WkR, Rws);

  // 4. fused scores+softmax+value-aggregate (block-per-token, deep prefetch)
  attn_fused<<<dim3(B_ * T_, 1), 256, 0, stream>>>(key, value, Rws, mask, gws, asum);

  // 5. x[bt,hd] = g_h @ Wv_h + asum*bv
  x_proj<<<dim3(16, 8), 256, 0, stream>>>(gws, WtV, bv, asum, xws);

  // 6. out = x@Wo + bo  (f32 out)
  gemm_pipe<false, true><<<dim3(128, 1), 256, 0, stream>>>(xws, WtO, bo, d_out, 1.0f);
}